// Round 1
// baseline (265.183 us; speedup 1.0000x reference)
//
#include <hip/hip_runtime.h>
#include <math.h>

// NUFFT forward, separable-phase factorization.
// ksp[c,k] = sum_x Ex[k,x] * ( sum_y img[c,x,y] * Ey[k,y] )
// Ex[k,x] = exp(-2*pi*i * kx * rx), rx = (x-64)/128; Ey analogous.
//
// Shapes: img (1,8,128,128) f32 re/im separate; trj (1,8192,2) f32; out (1,8,8192,2) f32.

#define K_TOTAL 8192
#define KB      16      // k's per block
#define CDIM    8
#define NX      128
#define NY      128

__global__ __launch_bounds__(256, 2) void nufft_fwd_kernel(
    const float* __restrict__ imgR,
    const float* __restrict__ imgI,
    const float* __restrict__ trj,
    float* __restrict__ out)
{
    __shared__ __align__(16) float eyC[KB][NY];
    __shared__ __align__(16) float eyS[KB][NY];
    __shared__ __align__(16) float exC[KB][NX];
    __shared__ __align__(16) float exS[KB][NX];

    const int tid = threadIdx.x;
    const int k0  = blockIdx.x * KB;

    // ---- Phase A: exponential tables (NX == NY so one loop fills both) ----
    for (int i = tid; i < KB * NY; i += 256) {
        const int kk = i >> 7;        // i / 128
        const int y  = i & 127;       // i % 128
        const float kx = trj[(k0 + kk) * 2 + 0];
        const float ky = trj[(k0 + kk) * 2 + 1];
        const float r  = (float)(y - 64) * (1.0f / 128.0f);   // in [-0.5, 0.5)

        // E = exp(-2*pi*i * k * r): t = -k*r revolutions; exact fract reduction.
        float ty = -ky * r;
        ty -= floorf(ty);
        float sy, cy;
        __sincosf(6.283185307179586f * ty, &sy, &cy);
        eyC[kk][y] = cy;
        eyS[kk][y] = sy;

        float tx = -kx * r;
        tx -= floorf(tx);
        float sx, cx;
        __sincosf(6.283185307179586f * tx, &sx, &cx);
        exC[kk][y] = cx;
        exS[kk][y] = sx;
    }
    __syncthreads();

    // ---- Phase B: thread = (coil c, x-group xg); 4 x-rows each ----
    const int c  = tid >> 5;   // 0..7
    const int xg = tid & 31;   // 0..31

    float accR[KB], accI[KB];
#pragma unroll
    for (int kk = 0; kk < KB; ++kk) { accR[kk] = 0.0f; accI[kk] = 0.0f; }

    for (int xi = 0; xi < 4; ++xi) {
        const int x = xg + 32 * xi;
        const float4* __restrict__ rowR = (const float4*)(imgR + (c * NX + x) * NY);
        const float4* __restrict__ rowI = (const float4*)(imgI + (c * NX + x) * NY);

        float TR[KB], TI[KB];
#pragma unroll
        for (int kk = 0; kk < KB; ++kk) { TR[kk] = 0.0f; TI[kk] = 0.0f; }

        for (int y4 = 0; y4 < NY / 4; ++y4) {
            const float4 aR = rowR[y4];
            const float4 aI = rowI[y4];
#pragma unroll
            for (int kk = 0; kk < KB; ++kk) {
                const float4 eC = *(const float4*)&eyC[kk][y4 * 4];  // wave-uniform: LDS broadcast
                const float4 eS = *(const float4*)&eyS[kk][y4 * 4];
                TR[kk] += aR.x * eC.x - aI.x * eS.x
                        + aR.y * eC.y - aI.y * eS.y
                        + aR.z * eC.z - aI.z * eS.z
                        + aR.w * eC.w - aI.w * eS.w;
                TI[kk] += aR.x * eS.x + aI.x * eC.x
                        + aR.y * eS.y + aI.y * eC.y
                        + aR.z * eS.z + aI.z * eC.z
                        + aR.w * eS.w + aI.w * eC.w;
            }
        }

#pragma unroll
        for (int kk = 0; kk < KB; ++kk) {
            const float ec = exC[kk][x];
            const float es = exS[kk][x];
            accR[kk] += ec * TR[kk] - es * TI[kk];
            accI[kk] += ec * TI[kk] + es * TR[kk];
        }
    }

    // ---- Reduce over the 32 xg lanes (same c, consecutive lanes) ----
#pragma unroll
    for (int kk = 0; kk < KB; ++kk) {
#pragma unroll
        for (int m = 16; m > 0; m >>= 1) {
            accR[kk] += __shfl_xor(accR[kk], m, 64);
            accI[kk] += __shfl_xor(accI[kk], m, 64);
        }
    }

    if (xg == 0) {
        float2* __restrict__ o = (float2*)out;
#pragma unroll
        for (int kk = 0; kk < KB; ++kk) {
            o[c * K_TOTAL + k0 + kk] = make_float2(accR[kk], accI[kk]);
        }
    }
}

extern "C" void kernel_launch(void* const* d_in, const int* in_sizes, int n_in,
                              void* d_out, int out_size, void* d_ws, size_t ws_size,
                              hipStream_t stream) {
    const float* imgR = (const float*)d_in[0];
    const float* imgI = (const float*)d_in[1];
    const float* trj  = (const float*)d_in[2];
    float* out = (float*)d_out;

    hipLaunchKernelGGL(nufft_fwd_kernel,
                       dim3(K_TOTAL / KB), dim3(256), 0, stream,
                       imgR, imgI, trj, out);
}

// Round 4
// 38.895 us; speedup vs baseline: 6.8179x; 6.8179x over previous
//
#include <hip/hip_runtime.h>
#include <math.h>

// NUFFT forward via separable phase + bf16 MFMA. No workspace.
// ksp[c,k] = sum_x Ex[k,x] * ( sum_y img[c,x,y] * Ey[k,y] )
// Stage 1 as complex bf16 GEMM on matrix cores (4 real MFMA accumulations);
// img fp32 -> bf16 converted in registers with EXPLICIT round-to-nearest-even
// (round-3 bug: __float2bfloat16 truncates on this ROCm -> absmax 16.5).

#define K_TOTAL 8192
#define KB      32          // k's per block
#define NX      128
#define NY      128
#define EY_LD   136         // bf16 row stride (pad +8)
#define EX_LD   132         // f32 row stride (pad +4)

typedef short  bf16x8 __attribute__((ext_vector_type(8)));
typedef float  f32x4  __attribute__((ext_vector_type(4)));

__device__ inline unsigned short f32_to_bf16_rne(float f) {
    unsigned int u = __float_as_uint(f);
    u += 0x7FFFu + ((u >> 16) & 1u);
    return (unsigned short)(u >> 16);
}

// 8 fp32 -> bf16x8, round-to-nearest-even (proven in round 2: absmax 2.0)
__device__ inline bf16x8 cvt8(const float4 a, const float4 b) {
    bf16x8 r;
    r[0] = (short)f32_to_bf16_rne(a.x);
    r[1] = (short)f32_to_bf16_rne(a.y);
    r[2] = (short)f32_to_bf16_rne(a.z);
    r[3] = (short)f32_to_bf16_rne(a.w);
    r[4] = (short)f32_to_bf16_rne(b.x);
    r[5] = (short)f32_to_bf16_rne(b.y);
    r[6] = (short)f32_to_bf16_rne(b.z);
    r[7] = (short)f32_to_bf16_rne(b.w);
    return r;
}

__global__ __launch_bounds__(512, 2) void nufft_mfma_kernel(
    const float* __restrict__ imgR,
    const float* __restrict__ imgI,
    const float* __restrict__ trj,
    float* __restrict__ out)
{
    __shared__ __align__(16) unsigned short eyR[KB][EY_LD];
    __shared__ __align__(16) unsigned short eyI[KB][EY_LD];
    __shared__ __align__(16) float exR[KB][EX_LD];
    __shared__ __align__(16) float exI[KB][EX_LD];

    const int tid = threadIdx.x;
    const int k0  = blockIdx.x * KB;

    // ---- Phase A: exponential tables (Ey bf16, Ex f32) ----
    for (int i = tid; i < KB * 128; i += 512) {
        const int kk = i >> 7;
        const int p  = i & 127;
        const float kx = trj[(k0 + kk) * 2 + 0];
        const float ky = trj[(k0 + kk) * 2 + 1];
        const float r  = (float)(p - 64) * (1.0f / 128.0f);

        float ty = -ky * r; ty -= floorf(ty);
        float sy, cy; __sincosf(6.283185307179586f * ty, &sy, &cy);
        eyR[kk][p] = f32_to_bf16_rne(cy);
        eyI[kk][p] = f32_to_bf16_rne(sy);

        float tx = -kx * r; tx -= floorf(tx);
        float sx, cx; __sincosf(6.283185307179586f * tx, &sx, &cx);
        exR[kk][p] = cx;
        exI[kk][p] = sx;
    }
    __syncthreads();

    const int wave = tid >> 6;      // 0..7  == coil
    const int lane = tid & 63;
    const int l15  = lane & 15;
    const int lg   = lane >> 4;     // 0..3

    // ---- A-fragment preload: Ey into registers (shared across all n-tiles) ----
    // A layout (16x16x32): row = lane&15 (+16*kt), k-dim slot = (lane>>4)*8 + idx.
    // A and B use the SAME k slot mapping, so any hw k-permutation cancels.
    bf16x8 aR[2][4], aI[2][4];
#pragma unroll
    for (int kt = 0; kt < 2; ++kt)
#pragma unroll
        for (int ys = 0; ys < 4; ++ys) {
            const int row = kt * 16 + l15;
            const int y   = ys * 32 + lg * 8;
            aR[kt][ys] = *(const bf16x8*)&eyR[row][y];
            aI[kt][ys] = *(const bf16x8*)&eyI[row][y];
        }

    const int c = wave;
    f32x4 outRe[2] = {{0,0,0,0},{0,0,0,0}};
    f32x4 outIm[2] = {{0,0,0,0},{0,0,0,0}};

    // ---- n-tiles: 8 x-tiles of 16 for this wave's coil ----
    for (int nt = 0; nt < 8; ++nt) {
        const int x = nt * 16 + l15;

        f32x4 P[2] = {{0,0,0,0},{0,0,0,0}};
        f32x4 Q[2] = {{0,0,0,0},{0,0,0,0}};
        f32x4 U[2] = {{0,0,0,0},{0,0,0,0}};
        f32x4 V[2] = {{0,0,0,0},{0,0,0,0}};

        // B layout: col = lane&15 -> x; k slot y = (lane>>4)*8 + idx, contiguous
        // in img[c][x][y]. Load fp32, convert in registers (RNE).
        const float* baseR = imgR + (c * NX + x) * NY + lg * 8;
        const float* baseI = imgI + (c * NX + x) * NY + lg * 8;

#pragma unroll
        for (int ys = 0; ys < 4; ++ys) {
            const float4 r0 = *(const float4*)(baseR + ys * 32);
            const float4 r1 = *(const float4*)(baseR + ys * 32 + 4);
            const float4 i0 = *(const float4*)(baseI + ys * 32);
            const float4 i1 = *(const float4*)(baseI + ys * 32 + 4);
            const bf16x8 bR = cvt8(r0, r1);
            const bf16x8 bI = cvt8(i0, i1);
#pragma unroll
            for (int kt = 0; kt < 2; ++kt) {
                P[kt] = __builtin_amdgcn_mfma_f32_16x16x32_bf16(aR[kt][ys], bR, P[kt], 0, 0, 0);
                Q[kt] = __builtin_amdgcn_mfma_f32_16x16x32_bf16(aI[kt][ys], bI, Q[kt], 0, 0, 0);
                U[kt] = __builtin_amdgcn_mfma_f32_16x16x32_bf16(aR[kt][ys], bI, U[kt], 0, 0, 0);
                V[kt] = __builtin_amdgcn_mfma_f32_16x16x32_bf16(aI[kt][ys], bR, V[kt], 0, 0, 0);
            }
        }

        // ---- Stage C: multiply by Ex[k,x], accumulate over this x-tile ----
        // C/D layout (m89-verified): col = lane&15 (x), row = (lane>>4)*4 + j (+16*kt)
#pragma unroll
        for (int kt = 0; kt < 2; ++kt) {
#pragma unroll
            for (int j = 0; j < 4; ++j) {
                const int kl = kt * 16 + lg * 4 + j;
                const float TR = P[kt][j] - Q[kt][j];
                const float TI = U[kt][j] + V[kt][j];
                const float eR = exR[kl][x];
                const float eI = exI[kl][x];
                outRe[kt][j] += eR * TR - eI * TI;
                outIm[kt][j] += eR * TI + eI * TR;
            }
        }
    }

    // ---- reduce over the 16 x-lanes; lanes with l15==0 write ----
#pragma unroll
    for (int kt = 0; kt < 2; ++kt) {
#pragma unroll
        for (int j = 0; j < 4; ++j) {
            float r_ = outRe[kt][j];
            float i_ = outIm[kt][j];
#pragma unroll
            for (int m = 1; m < 16; m <<= 1) {
                r_ += __shfl_xor(r_, m, 64);
                i_ += __shfl_xor(i_, m, 64);
            }
            if (l15 == 0) {
                const int kg = k0 + kt * 16 + lg * 4 + j;
                ((float2*)out)[c * K_TOTAL + kg] = make_float2(r_, i_);
            }
        }
    }
}

extern "C" void kernel_launch(void* const* d_in, const int* in_sizes, int n_in,
                              void* d_out, int out_size, void* d_ws, size_t ws_size,
                              hipStream_t stream) {
    const float* imgR = (const float*)d_in[0];
    const float* imgI = (const float*)d_in[1];
    const float* trj  = (const float*)d_in[2];
    float* out = (float*)d_out;

    hipLaunchKernelGGL(nufft_mfma_kernel, dim3(K_TOTAL / KB), dim3(512), 0, stream,
                       imgR, imgI, trj, out);
}